// Round 15
// baseline (150.021 us; speedup 1.0000x reference)
//
#include <hip/hip_runtime.h>

#define NB 16
#define CD 128
#define HD 64
#define WD 64
#define SD 4096   // H*W
#define K7 896    // 7*C
#define XROW 72   // padded row stride of xT (3 zero | 64 data | 5 zero)
#define SD2 4864  // xp2 plane stride: 76 rows * 64 (6 zero | 64 | 6 zero)

typedef float  f32x4  __attribute__((ext_vector_type(4)));
typedef __bf16 bf16x8 __attribute__((ext_vector_type(8)));
typedef __bf16 bf16x4 __attribute__((ext_vector_type(4)));

typedef __attribute__((address_space(3))) void lds_void_t;
typedef const __attribute__((address_space(1))) void gbl_void_t;

// async global->LDS, 16B/lane; LDS dest wave-uniform + lane*16, global per-lane
__device__ __forceinline__ void gl16(const void* g, void* l) {
  __builtin_amdgcn_global_load_lds((gbl_void_t*)g, (lds_void_t*)l, 16, 0, 0);
}

// counted wait (own DMAs, leave N in flight) + block barrier
template<int N>
__device__ __forceinline__ void vw() {
  __builtin_amdgcn_sched_barrier(0);
  asm volatile("s_waitcnt vmcnt(%0)" :: "i"(N) : "memory");
  __builtin_amdgcn_s_barrier();
  __builtin_amdgcn_sched_barrier(0);
}
__device__ __forceinline__ void barr() {
  __builtin_amdgcn_sched_barrier(0);
  __builtin_amdgcn_s_barrier();
  __builtin_amdgcn_sched_barrier(0);
}

// legacy counted barrier for m_mfma (NBUF=4 per-step pipeline)
template<int N>
__device__ __forceinline__ void wbar() {
  __builtin_amdgcn_sched_barrier(0);
  asm volatile("s_waitcnt vmcnt(%0)" :: "i"(N) : "memory");
  __builtin_amdgcn_s_barrier();
  __builtin_amdgcn_sched_barrier(0);
}

// ---------------------------------------------------------------------------
// prep: ximg cell layout + (optional) xp2 = bf16(x*p2), padded rows
// ---------------------------------------------------------------------------
__global__ __launch_bounds__(256)
void cvt_ximg(const float* __restrict__ x, const float* __restrict__ p2,
              __bf16* __restrict__ ximg, __bf16* __restrict__ xp2) {
  const int idx = (blockIdx.x * 256 + threadIdx.x) * 8;
  const float4 a = *(const float4*)(x + idx);
  const float4 b = *(const float4*)(x + idx + 4);
  bf16x8 v;
  v[0] = (__bf16)a.x; v[1] = (__bf16)a.y; v[2] = (__bf16)a.z; v[3] = (__bf16)a.w;
  v[4] = (__bf16)b.x; v[5] = (__bf16)b.y; v[6] = (__bf16)b.z; v[7] = (__bf16)b.w;
  const int plane = idx >> 12;          // n*CD + c
  const int n = plane >> 7, c = plane & 127;
  const int s0 = idx & 4095;
  const int stepg = s0 >> 5, kg = (s0 >> 3) & 3;
  *(bf16x8*)(ximg + ((size_t)((n * 128 + stepg) * 4 + kg) * 128 + c) * 8) = v;
  if (xp2) {
    const int j = s0 & 63;
    const float4 pa = *(const float4*)(p2 + c * 64 + j);
    const float4 pb = *(const float4*)(p2 + c * 64 + j + 4);
    bf16x8 w;
    w[0] = (__bf16)(a.x * pa.x); w[1] = (__bf16)(a.y * pa.y);
    w[2] = (__bf16)(a.z * pa.z); w[3] = (__bf16)(a.w * pa.w);
    w[4] = (__bf16)(b.x * pb.x); w[5] = (__bf16)(b.y * pb.y);
    w[6] = (__bf16)(b.z * pb.z); w[7] = (__bf16)(b.w * pb.w);
    *(bf16x8*)(xp2 + (size_t)plane * SD2 + 384 + s0) = w;
  }
}

// zero-fill xp2 pad rows (rows 0..5 and 70..75 of each plane)
__global__ __launch_bounds__(256)
void pad0_kernel(__bf16* __restrict__ xp2) {
  const int u = (blockIdx.x * 256 + threadIdx.x) * 8;   // < NB*CD*768
  const int plane = u / 768;
  const int r = u - plane * 768;
  const int off = (r < 384) ? r : (r + 4096);
  bf16x8 z = {};
  *(bf16x8*)(xp2 + (size_t)plane * SD2 + off) = z;
}

// ---------------------------------------------------------------------------
// prep: w7img image of (diag(p3)W7)^T in qmajor rows
// ---------------------------------------------------------------------------
__global__ __launch_bounds__(256)
void w7img_kernel(const float* __restrict__ w7, const float* __restrict__ p3,
                  __bf16* __restrict__ w7img) {
  __shared__ float tile[64][65];
  const int b2 = blockIdx.x * 64;   // k2 base
  const int bp = blockIdx.y * 64;   // k' base
  const int t  = threadIdx.x;
  const int col = t & 63;
  const int r0  = t >> 6;
#pragma unroll
  for (int rr = 0; rr < 16; ++rr) {
    const int row = rr * 4 + r0;
    tile[col][row] = w7[(size_t)(bp + row) * K7 + b2 + col];
  }
  __syncthreads();
  const int kpr = bp + col;
  const float p3v = p3[kpr];
#pragma unroll
  for (int rr = 0; rr < 16; ++rr) {
    const int row = rr * 4 + r0;
    const int k2  = b2 + row;
    const int c2  = k2 / 7, q = k2 - c2 * 7;
    const int k2q = q * 128 + c2;
    const size_t off = ((size_t)((k2q >> 6) * 28 + (kpr >> 5)) * 4 + ((kpr >> 3) & 3)) * 512
                     + (k2q & 63) * 8 + (kpr & 7);
    w7img[off] = (__bf16)(tile[row][col] * p3v);
  }
}

// ---------------------------------------------------------------------------
// prep: xT[n][i][j+3][c] = bf16(x[n][c][i][j]), rows 0..2 & 67..71 zero
// ---------------------------------------------------------------------------
__global__ __launch_bounds__(256)
void xt_kernel(const float* __restrict__ x, __bf16* __restrict__ xT) {
  __shared__ __bf16 tile[128][72];
  const int n = blockIdx.y;
  const int i = blockIdx.x;
  const int t = threadIdx.x;
  const float* src = x + (size_t)n * CD * SD + (size_t)i * WD;
#pragma unroll
  for (int it = 0; it < 4; ++it) {
    const int c = it * 32 + (t >> 3);
    const int j = (t & 7) * 8;
    const float* s2 = src + (size_t)c * SD + j;
    const float4 a = *(const float4*)s2;
    const float4 b = *(const float4*)(s2 + 4);
    bf16x8 v;
    v[0] = (__bf16)a.x; v[1] = (__bf16)a.y; v[2] = (__bf16)a.z; v[3] = (__bf16)a.w;
    v[4] = (__bf16)b.x; v[5] = (__bf16)b.y; v[6] = (__bf16)b.z; v[7] = (__bf16)b.w;
    *(bf16x8*)&tile[c][j] = v;
  }
  __bf16* dstn = xT + ((size_t)n * HD + i) * XROW * CD;
  if (t < 128) {
    const int pr = t >> 4;
    const int rowz = pr < 3 ? pr : 64 + pr;
    bf16x8 z = {};
    *(bf16x8*)(dstn + (size_t)rowz * CD + (t & 15) * 8) = z;
  }
  __syncthreads();
#pragma unroll
  for (int it = 0; it < 4; ++it) {
    const int j   = t >> 2;
    const int c2b = (t & 3) * 32 + it * 8;
    bf16x8 v;
#pragma unroll
    for (int e = 0; e < 8; ++e) v[e] = tile[c2b + e][j];
    *(bf16x8*)(dstn + (size_t)(j + 3) * CD + c2b) = v;
  }
}

// prep: p4T[i][j+3][c] = bf16(p4[c][i*64+j]), one xT-plane layout
__global__ __launch_bounds__(256)
void p4t_kernel(const float* __restrict__ p4, __bf16* __restrict__ p4T) {
  __shared__ __bf16 tile[128][72];
  const int i = blockIdx.x;
  const int t = threadIdx.x;
#pragma unroll
  for (int it = 0; it < 4; ++it) {
    const int c = it * 32 + (t >> 3);
    const int j = (t & 7) * 8;
    const float* src = p4 + (size_t)c * SD + (size_t)i * WD + j;
    const float4 a = *(const float4*)src;
    const float4 b = *(const float4*)(src + 4);
    bf16x8 v;
    v[0] = (__bf16)a.x; v[1] = (__bf16)a.y; v[2] = (__bf16)a.z; v[3] = (__bf16)a.w;
    v[4] = (__bf16)b.x; v[5] = (__bf16)b.y; v[6] = (__bf16)b.z; v[7] = (__bf16)b.w;
    *(bf16x8*)&tile[c][j] = v;
  }
  __bf16* dst = p4T + (size_t)i * XROW * CD;
  if (t < 128) {
    const int pr = t >> 4;
    const int rowz = pr < 3 ? pr : 64 + pr;
    bf16x8 z = {};
    *(bf16x8*)(dst + (size_t)rowz * CD + (t & 15) * 8) = z;
  }
  __syncthreads();
#pragma unroll
  for (int it = 0; it < 4; ++it) {
    const int j   = t >> 2;
    const int c2b = (t & 3) * 32 + it * 8;
    bf16x8 v;
#pragma unroll
    for (int e = 0; e < 8; ++e) v[e] = tile[c2b + e][j];
    *(bf16x8*)(dst + (size_t)(j + 3) * CD + c2b) = v;
  }
}

// ---------------------------------------------------------------------------
// reduce split-K bf16 partials [KC][2048][896] -> image [n][28][4][128][8]
// ---------------------------------------------------------------------------
template<int KC>
__global__ __launch_bounds__(256)
void reduce_img(const __bf16* __restrict__ part, __bf16* __restrict__ img,
                float scale) {
  const int idx8 = blockIdx.x * 256 + threadIdx.x;   // cell index, < 2048*112
  const int r = idx8 / 112;
  const int kchunk = idx8 - r * 112;
  const size_t in = (size_t)r * K7 + kchunk * 8;
  const size_t stride = (size_t)NB * CD * K7;
  float s[8];
  bf16x8 v = *(const bf16x8*)(part + in);
#pragma unroll
  for (int e = 0; e < 8; ++e) s[e] = (float)v[e];
#pragma unroll
  for (int c = 1; c < KC; ++c) {
    bf16x8 p = *(const bf16x8*)(part + c * stride + in);
#pragma unroll
    for (int e = 0; e < 8; ++e) s[e] += (float)p[e];
  }
  bf16x8 o;
#pragma unroll
  for (int e = 0; e < 8; ++e) o[e] = (__bf16)(s[e] * scale);
  const size_t out = ((size_t)(((r >> 7) * 28 + (kchunk >> 2)) * 4 + (kchunk & 3)) * 128
                      + (r & 127)) * 8;
  *(bf16x8*)(img + out) = o;
}

// std compute (m): A cells [kg][row], B cells [kg][row] (2-way aliasing = free)
#define COMPUTE_STD(AB, BB)                                                     \
  do {                                                                          \
    bf16x8 af[4], bfr[2];                                                       \
    _Pragma("unroll")                                                           \
    for (int fm = 0; fm < 4; ++fm)                                              \
      af[fm] = *(const bf16x8*)&As[AB][(lg * 128 + wm * 64 + fm * 16 + l16) * 8]; \
    _Pragma("unroll")                                                           \
    for (int fn = 0; fn < 2; ++fn)                                              \
      bfr[fn] = *(const bf16x8*)&Bs[BB][(lg * 64 + wn * 32 + fn * 16 + l16) * 8]; \
    _Pragma("unroll")                                                           \
    for (int fm = 0; fm < 4; ++fm)                                              \
      _Pragma("unroll")                                                         \
      for (int fn = 0; fn < 2; ++fn)                                            \
        acc[fm][fn] = __builtin_amdgcn_mfma_f32_16x16x32_bf16(af[fm], bfr[fn],  \
                                                              acc[fm][fn], 0, 0, 0); \
  } while (0)

// pair-B compute (t8/out): B cells [col rc][slot(8)], slot = (H*4+lg)^(rc&7);
// byte = rc*128 + slot*16 -> 2-way = free (round 8/10: 0 conflicts)
#define COMPUTE_SWZ(AB, BB, H)                                                  \
  do {                                                                          \
    bf16x8 af[4], bfr[2];                                                       \
    const int swz = ((((H) * 4 + lg) ^ (l16 & 7)) * 8);                         \
    _Pragma("unroll")                                                           \
    for (int fm = 0; fm < 4; ++fm)                                              \
      af[fm] = *(const bf16x8*)&As[AB][(lg * 128 + wm * 64 + fm * 16 + l16) * 8]; \
    _Pragma("unroll")                                                           \
    for (int fn = 0; fn < 2; ++fn)                                              \
      bfr[fn] = *(const bf16x8*)&Bs[BB][(wn * 32 + fn * 16 + l16) * 64 + swz];  \
    _Pragma("unroll")                                                           \
    for (int fm = 0; fm < 4; ++fm)                                              \
      _Pragma("unroll")                                                         \
      for (int fn = 0; fn < 2; ++fn)                                            \
        acc[fm][fn] = __builtin_amdgcn_mfma_f32_16x16x32_bf16(af[fm], bfr[fn],  \
                                                              acc[fm][fn], 0, 0, 0); \
  } while (0)

// ---------------------------------------------------------------------------
// GEMM 1 (split-K4): T8 partial. XP2: A=ximg DMA (4-step ring), B=xp2
// pair-DMA (2 pair bufs); 6-gl16 bundles issued 2 pairs ahead, vmcnt(6).
// grid flat 896, XCD-pinned (2 n per XCD).
// ---------------------------------------------------------------------------
template<bool XP2>
__global__ __launch_bounds__(256)
void t8_mfma(const float* __restrict__ x, const __bf16* __restrict__ ximg,
             const __bf16* __restrict__ xp2, const float* __restrict__ p2,
             __bf16* __restrict__ part) {
  __shared__ __bf16 As[XP2 ? 4 : 2][4096];
  __shared__ __bf16 Bs[2][4096];
  const int b = blockIdx.x;
  const int xcd = b & 7, slot0 = b >> 3;         // slot 0..111
  const int n  = xcd * 2 + slot0 / 56;
  const int r56 = slot0 % 56;
  const int kc = r56 / 14;
  const int n0 = (r56 % 14) * 64;
  const int t = threadIdx.x;
  const int lane = t & 63, wid = t >> 6;
  const int wm = wid & 1, wn = wid >> 1;
  const int l16 = lane & 15, lg = lane >> 4;
  const int wb = wid * 512;

  const __bf16* aptr = ximg + ((size_t)(n * 128 + kc * 32) * 512 + t) * 8;

  f32x4 acc[4][2] = {};

  if constexpr (XP2) {
    // B pair roles: 8 lanes per k'-row, rows rA=wid*16+(lane>>3), rB=rA+8
    const int rl = lane >> 3;
    const int sl = lane & 7;
    const int ch = sl ^ rl;                       // source chunk (XOR preswizzle)
    const int rA = wid * 16 + rl, rB = rA + 8;
    const int kpA = n0 + rA, kpB = n0 + rB;
    const int c2A = kpA / 7, kkA = kpA - c2A * 7;
    const int c2B = kpB / 7, kkB = kpB - c2B * 7;
    const __bf16* bptrA = xp2 + (size_t)(n * CD + c2A) * SD2
                        + (kc * 16 + 2 * kkA) * 64 + ch * 8;
    const __bf16* bptrB = xp2 + (size_t)(n * CD + c2B) * SD2
                        + (kc * 16 + 2 * kkB) * 64 + ch * 8;

#define TSTG(PP) do {                                                \
    const int a0_ = (2 * (PP)) & 3, a1_ = (2 * (PP) + 1) & 3;        \
    const int b_  = (PP) & 1;                                        \
    gl16(aptr + (size_t)(2 * (PP)) * 4096,            &As[a0_][wb]); \
    gl16(aptr + (size_t)(2 * (PP)) * 4096 + 2048,     &As[a0_][wb + 2048]); \
    gl16(aptr + (size_t)(2 * (PP) + 1) * 4096,        &As[a1_][wb]); \
    gl16(aptr + (size_t)(2 * (PP) + 1) * 4096 + 2048, &As[a1_][wb + 2048]); \
    gl16(bptrA + (PP) * 64, &Bs[b_][wid * 1024]);                    \
    gl16(bptrB + (PP) * 64, &Bs[b_][wid * 1024 + 512]);              \
  } while (0)

    const int P = 16;   // pairs; 32 steps
    TSTG(0); TSTG(1);
    for (int p = 0; p < P - 1; ++p) {
      vw<6>();                             // pair p fully landed (bundle p+1 in flight)
      COMPUTE_SWZ((2 * p) & 3, p & 1, 0);
      COMPUTE_SWZ((2 * p + 1) & 3, p & 1, 1);
      barr();                              // all waves done reading pair p's buffers
      if (p + 2 < P) TSTG(p + 2);          // overwrite freed buffers
    }
    vw<0>();
    COMPUTE_SWZ((2 * (P - 1)) & 3, (P - 1) & 1, 0);
    COMPUTE_SWZ((2 * (P - 1) + 1) & 3, (P - 1) & 1, 1);
#undef TSTG
  } else {
    // fallback: reg-gated B from f32 x (round-8 body, drain barriers)
    const int rw1 = wid * 16 + (lane >> 3);
    const int rw2 = rw1 + 8;
    const int kp1 = n0 + rw1, kp2 = n0 + rw2;
    const int c21 = kp1 / 7, kk1 = kp1 - c21 * 7;
    const int c22 = kp2 / 7, kk2 = kp2 - c22 * 7;
    const int scd = (lane & 7) ^ ((lane >> 3) & 7);
    const float* xr1 = x + ((size_t)n * CD + c21) * SD + scd * 8;
    const float* xr2 = x + ((size_t)n * CD + c22) * SD + scd * 8;
    float g1[8], g2[8];
#pragma unroll
    for (int e = 0; e < 8; ++e) {
      g1[e] = p2[c21 * WD + scd * 8 + e];
      g2[e] = p2[c22 * WD + scd * 8 + e];
    }
    const int d1 = rw1 * 64 + (lane & 7) * 8;
    const int d2 = d1 + 512;
    const int P = 16;
    float4 u10, u11, u20, u21;
    bool v1, v2;
#define T8A(B, ST) do {                                            \
    gl16(aptr + (size_t)(ST) * 4096,        &As[B][wb]);           \
    gl16(aptr + (size_t)(ST) * 4096 + 2048, &As[B][wb + 2048]);    \
  } while (0)
#define T8B_LOAD(PP) do {                                          \
    const int i_ = kc * 16 + (PP);                                 \
    const int ip1 = i_ + 2 * kk1 - 6, ip2 = i_ + 2 * kk2 - 6;      \
    v1 = ((unsigned)ip1 < (unsigned)HD);                           \
    v2 = ((unsigned)ip2 < (unsigned)HD);                           \
    if (v1) { u10 = *(const float4*)(xr1 + ip1 * 64);              \
              u11 = *(const float4*)(xr1 + ip1 * 64 + 4); }        \
    if (v2) { u20 = *(const float4*)(xr2 + ip2 * 64);              \
              u21 = *(const float4*)(xr2 + ip2 * 64 + 4); }        \
  } while (0)
#define T8B_WRITE(B) do {                                          \
    bf16x8 b1 = {}, b2 = {};                                       \
    if (v1) {                                                      \
      b1[0]=(__bf16)(u10.x*g1[0]); b1[1]=(__bf16)(u10.y*g1[1]);    \
      b1[2]=(__bf16)(u10.z*g1[2]); b1[3]=(__bf16)(u10.w*g1[3]);    \
      b1[4]=(__bf16)(u11.x*g1[4]); b1[5]=(__bf16)(u11.y*g1[5]);    \
      b1[6]=(__bf16)(u11.z*g1[6]); b1[7]=(__bf16)(u11.w*g1[7]);    \
    }                                                              \
    if (v2) {                                                      \
      b2[0]=(__bf16)(u20.x*g2[0]); b2[1]=(__bf16)(u20.y*g2[1]);    \
      b2[2]=(__bf16)(u20.z*g2[2]); b2[3]=(__bf16)(u20.w*g2[3]);    \
      b2[4]=(__bf16)(u21.x*g2[4]); b2[5]=(__bf16)(u21.y*g2[5]);    \
      b2[6]=(__bf16)(u21.z*g2[6]); b2[7]=(__bf16)(u21.w*g2[7]);    \
    }                                                              \
    *(bf16x8*)&Bs[B][d1] = b1;                                     \
    *(bf16x8*)&Bs[B][d2] = b2;                                     \
  } while (0)
    T8B_LOAD(0);
    T8A(0, 0);
    T8B_WRITE(0);
    __syncthreads();
    for (int p = 0; p < P; ++p) {
      const int pb = p & 1;
      if (p + 1 < P) T8B_LOAD(p + 1);
      T8A(1, 2 * p + 1);
      COMPUTE_SWZ(0, pb, 0);
      if (p + 1 < P) T8B_WRITE(pb ^ 1);
      __syncthreads();
      if (p + 1 < P) T8A(0, 2 * p + 2);
      COMPUTE_SWZ(1, pb, 1);
      __syncthreads();
    }
#undef T8A
#undef T8B_LOAD
#undef T8B_WRITE
  }

  const int colb = n0 + wn * 32 + l16;
  __bf16* pb2 = part + ((size_t)(kc * NB + n) * CD) * K7;
#pragma unroll
  for (int fm = 0; fm < 4; ++fm)
#pragma unroll
    for (int r2 = 0; r2 < 4; ++r2) {
      const int c1 = wm * 64 + fm * 16 + lg * 4 + r2;
      __bf16* orow = pb2 + (size_t)c1 * K7 + colb;
      orow[0]  = (__bf16)acc[fm][0][r2];
      orow[16] = (__bf16)acc[fm][1][r2];
    }
}

// ---------------------------------------------------------------------------
// GEMM 2 (split-K2): M = T8 · (diag(p3)·W7). Pure-DMA, wbar NBUF=4 (validated).
// ---------------------------------------------------------------------------
__global__ __launch_bounds__(256)
void m_mfma(const __bf16* __restrict__ t8img, const __bf16* __restrict__ w7img,
            __bf16* __restrict__ part) {
  __shared__ __bf16 As[4][4096];
  __shared__ __bf16 Bs[4][2048];
  const int tile = blockIdx.x;
  const int n    = blockIdx.y;
  const int kc   = blockIdx.z;
  const int t = threadIdx.x;
  const int lane = t & 63, wid = t >> 6;
  const int wm = wid & 1, wn = wid >> 1;
  const int l16 = lane & 15, lg = lane >> 4;
  const int wb = wid * 512;

  const __bf16* aptr = t8img + ((size_t)(n * 28 + kc * 14) * 512 + t) * 8;
  const __bf16* bptr = w7img + ((size_t)(tile * 28 + kc * 14) * 256 + t) * 8;

  f32x4 acc[4][2] = {};
  const int NSTEP = 14;

#define M_STG(B, ST) do {                                          \
    gl16(aptr + (size_t)(ST) * 4096,        &As[B][wb]);           \
    gl16(aptr + (size_t)(ST) * 4096 + 2048, &As[B][wb + 2048]);    \
    gl16(bptr + (size_t)(ST) * 2048,        &Bs[B][wb]);           \
  } while (0)

  M_STG(0, 0); M_STG(1, 1); M_STG(2, 2);
  for (int st = 0; st < NSTEP - 2; ++st) {
    wbar<6>();
    if (st + 3 < NSTEP) M_STG((st + 3) & 3, st + 3);
    COMPUTE_STD(st & 3, st & 3);
  }
  wbar<3>(); COMPUTE_STD((NSTEP - 2) & 3, (NSTEP - 2) & 3);
  wbar<0>(); COMPUTE_STD((NSTEP - 1) & 3, (NSTEP - 1) & 3);
#undef M_STG

  const int colb = tile * 64 + wn * 32 + l16;
  __bf16* pb = part + (size_t)kc * (NB * CD * K7);
#pragma unroll
  for (int fm = 0; fm < 4; ++fm)
#pragma unroll
    for (int r = 0; r < 4; ++r) {
      const int mr = n * 128 + wm * 64 + fm * 16 + lg * 4 + r;
      __bf16* orow = pb + (size_t)mr * K7 + colb;
      orow[0]  = (__bf16)acc[fm][0][r];
      orow[16] = (__bf16)acc[fm][1][r];
    }
}

// ---------------------------------------------------------------------------
// GEMM 3: out = M·Bx - t6. A=mimg DMA (4-step ring); B=xT pair-DMA (2 bufs);
// 6-gl16 bundles 2 pairs ahead, vmcnt(6). grid flat 1024, XCD-pinned.
// ---------------------------------------------------------------------------
__global__ __launch_bounds__(256)
void out_mfma(const __bf16* __restrict__ mimg, const __bf16* __restrict__ xT,
              const __bf16* __restrict__ p4T, const float* __restrict__ w6,
              float* __restrict__ outp) {
  __shared__ __bf16 As[4][4096];
  __shared__ __bf16 Bs[2][4096];
  const int b = blockIdx.x;
  const int xcd = b & 7, slot0 = b >> 3;         // slot 0..127
  const int n = (xcd << 1) | (slot0 >> 6);
  const int i = slot0 & 63;
  const int t = threadIdx.x;
  const int lane = t & 63, wid = t >> 6;
  const int wm = wid & 1, wn = wid >> 1;
  const int l16 = lane & 15, lg = lane >> 4;
  const int wb = wid * 512;

  const __bf16* aptr = mimg + ((size_t)n * 28 * 512 + t) * 8;

  // B pair roles: 8 lanes/col, cols wid*16+(lane>>3) and +8; chunk XOR preswz
  const int colw = wid * 16 + (lane >> 3);
  const int scd8 = ((lane & 7) ^ ((lane >> 3) & 7)) * 8;
  const __bf16* bptr1 = xT + (((size_t)n * HD + i) * XROW + colw) * CD + scd8;
  const __bf16* bptr2 = bptr1 + 8 * CD;

  f32x4 acc[4][2] = {};

#define OSTG(PP) do {                                                \
    const int a0_ = (2 * (PP)) & 3, a1_ = (2 * (PP) + 1) & 3;        \
    const int b_  = (PP) & 1;                                        \
    gl16(aptr + (size_t)(2 * (PP)) * 4096,            &As[a0_][wb]); \
    gl16(aptr + (size_t)(2 * (PP)) * 4096 + 2048,     &As[a0_][wb + 2048]); \
    gl16(aptr + (size_t)(2 * (PP) + 1) * 4096,        &As[a1_][wb]); \
    gl16(aptr + (size_t)(2 * (PP) + 1) * 4096 + 2048, &As[a1_][wb + 2048]); \
    gl16(bptr1 + (PP) * 64, &Bs[b_][wid * 1024]);                    \
    gl16(bptr2 + (PP) * 64, &Bs[b_][wid * 1024 + 512]);              \
  } while (0)

  const int P = 14;   // pairs; 28 steps
  OSTG(0); OSTG(1);
  for (int p = 0; p < P - 1; ++p) {
    vw<6>();
    COMPUTE_SWZ((2 * p) & 3, p & 1, 0);
    COMPUTE_SWZ((2 * p + 1) & 3, p & 1, 1);
    barr();
    if (p + 2 < P) OSTG(p + 2);
  }
  vw<0>();
  COMPUTE_SWZ((2 * (P - 1)) & 3, (P - 1) & 1, 0);
  COMPUTE_SWZ((2 * (P - 1) + 1) & 3, (P - 1) & 1, 1);
#undef OSTG

  // epilogue: subtract depthwise t6 (xT/p4T channel-contiguous reads)
  const __bf16* xTn = xT + (size_t)n * HD * XROW * CD;
#pragma unroll
  for (int fm = 0; fm < 4; ++fm) {
    const int cbase = wm * 64 + fm * 16 + lg * 4;
    const float4 wa  = *(const float4*)(w6 + cbase * 3);
    const float4 wbv = *(const float4*)(w6 + cbase * 3 + 4);
    const float4 wc  = *(const float4*)(w6 + cbase * 3 + 8);
    const float w6v[4][3] = {{wa.x, wa.y, wa.z}, {wa.w, wbv.x, wbv.y},
                             {wbv.z, wbv.w, wc.x}, {wc.y, wc.z, wc.w}};
#pragma unroll
    for (int fn = 0; fn < 2; ++fn) {
      const int jj = wn * 32 + fn * 16 + l16;
      const int jm = (jj - 1) & 63;
      const size_t ro = (size_t)(jm + 3) * CD + cbase;
      float t6v[4] = {0.f, 0.f, 0.f, 0.f};
#pragma unroll
      for (int rr = 0; rr < 3; ++rr) {
        const int ip = i + 3 * rr - 3;
        if ((unsigned)ip < (unsigned)HD) {
          const bf16x4 xv = *(const bf16x4*)(xTn + (size_t)ip * XROW * CD + ro);
          const bf16x4 pv = *(const bf16x4*)(p4T + (size_t)ip * XROW * CD + ro);
#pragma unroll
          for (int rq = 0; rq < 4; ++rq)
            t6v[rq] += w6v[rq][rr] * (float)pv[rq] * (float)xv[rq];
        }
      }
      float* obase = outp + ((size_t)(n * CD + cbase)) * SD + i * WD + jj;
#pragma unroll
      for (int rq = 0; rq < 4; ++rq)
        obase[(size_t)rq * SD] = acc[fm][fn][rq] - t6v[rq];
    }
  }
}

extern "C" void kernel_launch(void* const* d_in, const int* in_sizes, int n_in,
                              void* d_out, int out_size, void* d_ws, size_t ws_size,
                              hipStream_t stream) {
  const float* x  = (const float*)d_in[0];
  const float* p2 = (const float*)d_in[1];
  const float* p3 = (const float*)d_in[2];
  const float* p4 = (const float*)d_in[3];
  const float* w6 = (const float*)d_in[4];
  const float* w7 = (const float*)d_in[5];
  float* outp = (float*)d_out;

  const size_t e_x   = (size_t)NB * CD * SD;          // 8,388,608
  const size_t e_t8  = (size_t)NB * CD * K7;          // 1,835,008
  const size_t e_w7  = (size_t)K7 * K7;               //   802,816
  const size_t e_xp2 = (size_t)NB * CD * SD2;         // 9,961,472
  const size_t e_xT  = (size_t)NB * HD * XROW * CD;   // 9,437,184
  const size_t e_p4T = (size_t)HD * XROW * CD;        //   589,824

  const size_t base_b = (e_x + 2 * e_t8 + e_w7) * 2;              // 25,722,880
  const size_t xp2_b  = (e_xp2 + 4 * e_t8) * 2;                   // 34,603,008
  const bool   tierA  = ws_size >= base_b + xp2_b;                // 60,325,888

  __bf16* ximg  = (__bf16*)d_ws;
  __bf16* t8img = ximg + e_x;
  __bf16* mimg  = t8img + e_t8;
  __bf16* w7img = mimg + e_t8;
  __bf16* region = w7img + e_w7;
  __bf16* xp2    = tierA ? region : nullptr;
  __bf16* partT8 = tierA ? (region + e_xp2) : region;  // dead after reduce4
  __bf16* partM  = region;                             // dead after reduce2
  __bf16* xT     = region;                             // built after reduce2
  __bf16* p4T    = region + e_xT;

  dim3 blk(256);
  cvt_ximg<<<dim3((unsigned)(e_x / 2048)), blk, 0, stream>>>(x, p2, ximg, xp2);
  if (tierA)
    pad0_kernel<<<dim3((unsigned)(NB * CD * 768 / 2048)), blk, 0, stream>>>(xp2);
  w7img_kernel<<<dim3(14, 14), blk, 0, stream>>>(w7, p3, w7img);

  if (tierA)
    t8_mfma<true><<<dim3(896), blk, 0, stream>>>(x, ximg, xp2, p2, partT8);
  else
    t8_mfma<false><<<dim3(896), blk, 0, stream>>>(x, ximg, nullptr, p2, partT8);
  reduce_img<4><<<dim3(896), blk, 0, stream>>>(partT8, t8img, 1.f / 64.f);

  m_mfma<<<dim3(14, 16, 2), blk, 0, stream>>>(t8img, w7img, partM);
  reduce_img<2><<<dim3(896), blk, 0, stream>>>(partM, mimg, 0.033407655f);

  xt_kernel<<<dim3(HD, NB), blk, 0, stream>>>(x, xT);
  p4t_kernel<<<dim3(HD), blk, 0, stream>>>(p4, p4T);
  out_mfma<<<dim3(1024), blk, 0, stream>>>(mimg, xT, p4T, w6, outp);
}

// Round 16
// 126.204 us; speedup vs baseline: 1.1887x; 1.1887x over previous
//
#include <hip/hip_runtime.h>

#define NB 16
#define CD 128
#define HD 64
#define WD 64
#define SD 4096   // H*W
#define K7 896    // 7*C
#define XROW 72   // padded row stride of xT (3 zero | 64 data | 5 zero)
#define SD2 4864  // xp2 plane stride: 76 rows * 64 (6 zero | 64 | 6 zero)

typedef float  f32x4  __attribute__((ext_vector_type(4)));
typedef __bf16 bf16x8 __attribute__((ext_vector_type(8)));
typedef __bf16 bf16x4 __attribute__((ext_vector_type(4)));

typedef __attribute__((address_space(3))) void lds_void_t;
typedef const __attribute__((address_space(1))) void gbl_void_t;

// async global->LDS, 16B/lane; LDS dest wave-uniform + lane*16, global per-lane
__device__ __forceinline__ void gl16(const void* g, void* l) {
  __builtin_amdgcn_global_load_lds((gbl_void_t*)g, (lds_void_t*)l, 16, 0, 0);
}

// counted wait (own DMAs, leave N in flight) + block barrier
template<int N>
__device__ __forceinline__ void vw() {
  __builtin_amdgcn_sched_barrier(0);
  asm volatile("s_waitcnt vmcnt(%0)" :: "i"(N) : "memory");
  __builtin_amdgcn_s_barrier();
  __builtin_amdgcn_sched_barrier(0);
}
__device__ __forceinline__ void barr() {
  __builtin_amdgcn_sched_barrier(0);
  __builtin_amdgcn_s_barrier();
  __builtin_amdgcn_sched_barrier(0);
}

// ---------------------------------------------------------------------------
// prep: ximg cell layout + (optional) xp2 = bf16(x*p2) with padded rows.
// Tail blocks (>= 4096) zero-fill xp2 pad rows (fused old pad0_kernel).
// ---------------------------------------------------------------------------
__global__ __launch_bounds__(256)
void cvt_ximg(const float* __restrict__ x, const float* __restrict__ p2,
              __bf16* __restrict__ ximg, __bf16* __restrict__ xp2) {
  if (blockIdx.x >= 4096) {            // pad-fill tail (768 blocks)
    if (!xp2) return;
    const int u = ((blockIdx.x - 4096) * 256 + threadIdx.x) * 8;  // < NB*CD*768
    const int plane = u / 768;
    const int r = u - plane * 768;
    const int off = (r < 384) ? r : (r + 4096);
    bf16x8 z = {};
    *(bf16x8*)(xp2 + (size_t)plane * SD2 + off) = z;
    return;
  }
  const int idx = (blockIdx.x * 256 + threadIdx.x) * 8;
  const float4 a = *(const float4*)(x + idx);
  const float4 b = *(const float4*)(x + idx + 4);
  bf16x8 v;
  v[0] = (__bf16)a.x; v[1] = (__bf16)a.y; v[2] = (__bf16)a.z; v[3] = (__bf16)a.w;
  v[4] = (__bf16)b.x; v[5] = (__bf16)b.y; v[6] = (__bf16)b.z; v[7] = (__bf16)b.w;
  const int plane = idx >> 12;          // n*CD + c
  const int n = plane >> 7, c = plane & 127;
  const int s0 = idx & 4095;
  const int stepg = s0 >> 5, kg = (s0 >> 3) & 3;
  *(bf16x8*)(ximg + ((size_t)((n * 128 + stepg) * 4 + kg) * 128 + c) * 8) = v;
  if (xp2) {
    const int j = s0 & 63;
    const float4 pa = *(const float4*)(p2 + c * 64 + j);
    const float4 pb = *(const float4*)(p2 + c * 64 + j + 4);
    bf16x8 w;
    w[0] = (__bf16)(a.x * pa.x); w[1] = (__bf16)(a.y * pa.y);
    w[2] = (__bf16)(a.z * pa.z); w[3] = (__bf16)(a.w * pa.w);
    w[4] = (__bf16)(b.x * pb.x); w[5] = (__bf16)(b.y * pb.y);
    w[6] = (__bf16)(b.z * pb.z); w[7] = (__bf16)(b.w * pb.w);
    *(bf16x8*)(xp2 + (size_t)plane * SD2 + 384 + s0) = w;
  }
}

// ---------------------------------------------------------------------------
// prep: w7img image of (diag(p3)W7)^T in qmajor rows
// ---------------------------------------------------------------------------
__global__ __launch_bounds__(256)
void w7img_kernel(const float* __restrict__ w7, const float* __restrict__ p3,
                  __bf16* __restrict__ w7img) {
  __shared__ float tile[64][65];
  const int b2 = blockIdx.x * 64;   // k2 base
  const int bp = blockIdx.y * 64;   // k' base
  const int t  = threadIdx.x;
  const int col = t & 63;
  const int r0  = t >> 6;
#pragma unroll
  for (int rr = 0; rr < 16; ++rr) {
    const int row = rr * 4 + r0;
    tile[col][row] = w7[(size_t)(bp + row) * K7 + b2 + col];
  }
  __syncthreads();
  const int kpr = bp + col;
  const float p3v = p3[kpr];
#pragma unroll
  for (int rr = 0; rr < 16; ++rr) {
    const int row = rr * 4 + r0;
    const int k2  = b2 + row;
    const int c2  = k2 / 7, q = k2 - c2 * 7;
    const int k2q = q * 128 + c2;
    const size_t off = ((size_t)((k2q >> 6) * 28 + (kpr >> 5)) * 4 + ((kpr >> 3) & 3)) * 512
                     + (k2q & 63) * 8 + (kpr & 7);
    w7img[off] = (__bf16)(tile[row][col] * p3v);
  }
}

// ---------------------------------------------------------------------------
// prep (fused): y<NB -> xT[n][i][j+3][c] = bf16(x[n][c][i][j]);
//               y==NB -> p4T[i][j+3][c]  = bf16(p4[c][i*64+j]).
// Pad rows 0..2 & 67..71 zeroed in both.
// ---------------------------------------------------------------------------
__global__ __launch_bounds__(256)
void xt_kernel(const float* __restrict__ x, const float* __restrict__ p4,
               __bf16* __restrict__ xT, __bf16* __restrict__ p4T) {
  __shared__ __bf16 tile[128][72];
  const int n = blockIdx.y;
  const int i = blockIdx.x;
  const int t = threadIdx.x;
  const float* src = (n < NB) ? x + (size_t)n * CD * SD + (size_t)i * WD
                              : p4 + (size_t)i * WD;
  __bf16* dstn = (n < NB) ? xT + ((size_t)n * HD + i) * XROW * CD
                          : p4T + (size_t)i * XROW * CD;
#pragma unroll
  for (int it = 0; it < 4; ++it) {
    const int c = it * 32 + (t >> 3);
    const int j = (t & 7) * 8;
    const float* s2 = src + (size_t)c * SD + j;
    const float4 a = *(const float4*)s2;
    const float4 b = *(const float4*)(s2 + 4);
    bf16x8 v;
    v[0] = (__bf16)a.x; v[1] = (__bf16)a.y; v[2] = (__bf16)a.z; v[3] = (__bf16)a.w;
    v[4] = (__bf16)b.x; v[5] = (__bf16)b.y; v[6] = (__bf16)b.z; v[7] = (__bf16)b.w;
    *(bf16x8*)&tile[c][j] = v;
  }
  if (t < 128) {
    const int pr = t >> 4;
    const int rowz = pr < 3 ? pr : 64 + pr;
    bf16x8 z = {};
    *(bf16x8*)(dstn + (size_t)rowz * CD + (t & 15) * 8) = z;
  }
  __syncthreads();
#pragma unroll
  for (int it = 0; it < 4; ++it) {
    const int j   = t >> 2;
    const int c2b = (t & 3) * 32 + it * 8;
    bf16x8 v;
#pragma unroll
    for (int e = 0; e < 8; ++e) v[e] = tile[c2b + e][j];
    *(bf16x8*)(dstn + (size_t)(j + 3) * CD + c2b) = v;
  }
}

// ---------------------------------------------------------------------------
// reduce split-K bf16 partials [KC][2048][896] -> image [n][28][4][128][8]
// ---------------------------------------------------------------------------
template<int KC>
__global__ __launch_bounds__(256)
void reduce_img(const __bf16* __restrict__ part, __bf16* __restrict__ img,
                float scale) {
  const int idx8 = blockIdx.x * 256 + threadIdx.x;   // cell index, < 2048*112
  const int r = idx8 / 112;
  const int kchunk = idx8 - r * 112;
  const size_t in = (size_t)r * K7 + kchunk * 8;
  const size_t stride = (size_t)NB * CD * K7;
  float s[8];
  bf16x8 v = *(const bf16x8*)(part + in);
#pragma unroll
  for (int e = 0; e < 8; ++e) s[e] = (float)v[e];
#pragma unroll
  for (int c = 1; c < KC; ++c) {
    bf16x8 p = *(const bf16x8*)(part + c * stride + in);
#pragma unroll
    for (int e = 0; e < 8; ++e) s[e] += (float)p[e];
  }
  bf16x8 o;
#pragma unroll
  for (int e = 0; e < 8; ++e) o[e] = (__bf16)(s[e] * scale);
  const size_t out = ((size_t)(((r >> 7) * 28 + (kchunk >> 2)) * 4 + (kchunk & 3)) * 128
                      + (r & 127)) * 8;
  *(bf16x8*)(img + out) = o;
}

// std compute (m): A cells [kg][row], B cells [kg][row] (2-way aliasing = free)
#define COMPUTE_STD(AB, BB)                                                     \
  do {                                                                          \
    bf16x8 af[4], bfr[2];                                                       \
    _Pragma("unroll")                                                           \
    for (int fm = 0; fm < 4; ++fm)                                              \
      af[fm] = *(const bf16x8*)&As[AB][(lg * 128 + wm * 64 + fm * 16 + l16) * 8]; \
    _Pragma("unroll")                                                           \
    for (int fn = 0; fn < 2; ++fn)                                              \
      bfr[fn] = *(const bf16x8*)&Bs[BB][(lg * 64 + wn * 32 + fn * 16 + l16) * 8]; \
    _Pragma("unroll")                                                           \
    for (int fm = 0; fm < 4; ++fm)                                              \
      _Pragma("unroll")                                                         \
      for (int fn = 0; fn < 2; ++fn)                                            \
        acc[fm][fn] = __builtin_amdgcn_mfma_f32_16x16x32_bf16(af[fm], bfr[fn],  \
                                                              acc[fm][fn], 0, 0, 0); \
  } while (0)

// pair-B compute (t8/out): B cells [col rc][slot(8)], slot = (H*4+lg)^(rc&7);
// byte = rc*128 + slot*16 -> 2-way = free (rounds 8/10: 0 conflicts).
// T5: setprio(1) around the MFMA cluster (phase-split pipeline -> pays).
#define COMPUTE_SWZ(AB, BB, H)                                                  \
  do {                                                                          \
    bf16x8 af[4], bfr[2];                                                       \
    const int swz = ((((H) * 4 + lg) ^ (l16 & 7)) * 8);                         \
    _Pragma("unroll")                                                           \
    for (int fm = 0; fm < 4; ++fm)                                              \
      af[fm] = *(const bf16x8*)&As[AB][(lg * 128 + wm * 64 + fm * 16 + l16) * 8]; \
    _Pragma("unroll")                                                           \
    for (int fn = 0; fn < 2; ++fn)                                              \
      bfr[fn] = *(const bf16x8*)&Bs[BB][(wn * 32 + fn * 16 + l16) * 64 + swz];  \
    __builtin_amdgcn_s_setprio(1);                                              \
    _Pragma("unroll")                                                           \
    for (int fm = 0; fm < 4; ++fm)                                              \
      _Pragma("unroll")                                                         \
      for (int fn = 0; fn < 2; ++fn)                                            \
        acc[fm][fn] = __builtin_amdgcn_mfma_f32_16x16x32_bf16(af[fm], bfr[fn],  \
                                                              acc[fm][fn], 0, 0, 0); \
    __builtin_amdgcn_s_setprio(0);                                              \
  } while (0)

// ---------------------------------------------------------------------------
// GEMM 1 (split-K4): T8 partial. XP2: A=ximg DMA, B=xp2 pair-DMA (8 lanes/row,
// 128B segments, source-XOR-preswizzled), 2-buf counted-vmcnt pipeline.
// grid flat 896, XCD-pinned (2 n per XCD).  [proven 129.8us config]
// ---------------------------------------------------------------------------
template<bool XP2>
__global__ __launch_bounds__(256)
void t8_mfma(const float* __restrict__ x, const __bf16* __restrict__ ximg,
             const __bf16* __restrict__ xp2, const float* __restrict__ p2,
             __bf16* __restrict__ part) {
  __shared__ __bf16 As[2][4096];
  __shared__ __bf16 Bs[2][4096];
  const int b = blockIdx.x;
  const int xcd = b & 7, slot0 = b >> 3;         // slot 0..111
  const int n  = xcd * 2 + slot0 / 56;
  const int r56 = slot0 % 56;
  const int kc = r56 / 14;
  const int n0 = (r56 % 14) * 64;
  const int t = threadIdx.x;
  const int lane = t & 63, wid = t >> 6;
  const int wm = wid & 1, wn = wid >> 1;
  const int l16 = lane & 15, lg = lane >> 4;
  const int wb = wid * 512;

  const __bf16* aptr = ximg + ((size_t)(n * 128 + kc * 32) * 512 + t) * 8;

  f32x4 acc[4][2] = {};

  if constexpr (XP2) {
    const int rl = lane >> 3;
    const int sl = lane & 7;
    const int ch = sl ^ rl;                       // source chunk (XOR preswizzle)
    const int rA = wid * 16 + rl, rB = rA + 8;
    const int kpA = n0 + rA, kpB = n0 + rB;
    const int c2A = kpA / 7, kkA = kpA - c2A * 7;
    const int c2B = kpB / 7, kkB = kpB - c2B * 7;
    const __bf16* bptrA = xp2 + (size_t)(n * CD + c2A) * SD2
                        + (kc * 16 + 2 * kkA) * 64 + ch * 8;
    const __bf16* bptrB = xp2 + (size_t)(n * CD + c2B) * SD2
                        + (kc * 16 + 2 * kkB) * 64 + ch * 8;

#define T8A(B, ST) do {                                            \
    gl16(aptr + (size_t)(ST) * 4096,        &As[B][wb]);           \
    gl16(aptr + (size_t)(ST) * 4096 + 2048, &As[B][wb + 2048]);    \
  } while (0)
#define T8B(B, PP) do {                                            \
    gl16(bptrA + (PP) * 64, &Bs[B][wid * 1024]);                   \
    gl16(bptrB + (PP) * 64, &Bs[B][wid * 1024 + 512]);             \
  } while (0)

    const int P = 16;   // pairs; 32 steps
    T8A(0, 0); T8B(0, 0);
    for (int p = 0; p < P - 1; ++p) {
      const int pb = p & 1;
      T8A(1, 2 * p + 1);
      T8B(pb ^ 1, p + 1);
      vw<4>();                       // A(even,2p)+B(p) landed everywhere
      COMPUTE_SWZ(0, pb, 0);
      vw<2>();                       // A(odd,2p+1) landed; all done reading As[0]
      T8A(0, 2 * p + 2);
      COMPUTE_SWZ(1, pb, 1);
      barr();                        // all done pair p -> next issues safe
    }
    { const int pb = (P - 1) & 1;
      T8A(1, 2 * P - 1);
      vw<2>();
      COMPUTE_SWZ(0, pb, 0);
      vw<0>();
      COMPUTE_SWZ(1, pb, 1);
    }
#undef T8A
#undef T8B
  } else {
    // fallback: reg-gated B from f32 x (round-8 body, drain barriers)
    const int rw1 = wid * 16 + (lane >> 3);
    const int rw2 = rw1 + 8;
    const int kp1 = n0 + rw1, kp2 = n0 + rw2;
    const int c21 = kp1 / 7, kk1 = kp1 - c21 * 7;
    const int c22 = kp2 / 7, kk2 = kp2 - c22 * 7;
    const int scd = (lane & 7) ^ ((lane >> 3) & 7);
    const float* xr1 = x + ((size_t)n * CD + c21) * SD + scd * 8;
    const float* xr2 = x + ((size_t)n * CD + c22) * SD + scd * 8;
    float g1[8], g2[8];
#pragma unroll
    for (int e = 0; e < 8; ++e) {
      g1[e] = p2[c21 * WD + scd * 8 + e];
      g2[e] = p2[c22 * WD + scd * 8 + e];
    }
    const int d1 = rw1 * 64 + (lane & 7) * 8;
    const int d2 = d1 + 512;
    const int P = 16;
    float4 u10, u11, u20, u21;
    bool v1, v2;
#define T8A(B, ST) do {                                            \
    gl16(aptr + (size_t)(ST) * 4096,        &As[B][wb]);           \
    gl16(aptr + (size_t)(ST) * 4096 + 2048, &As[B][wb + 2048]);    \
  } while (0)
#define T8B_LOAD(PP) do {                                          \
    const int i_ = kc * 16 + (PP);                                 \
    const int ip1 = i_ + 2 * kk1 - 6, ip2 = i_ + 2 * kk2 - 6;      \
    v1 = ((unsigned)ip1 < (unsigned)HD);                           \
    v2 = ((unsigned)ip2 < (unsigned)HD);                           \
    if (v1) { u10 = *(const float4*)(xr1 + ip1 * 64);              \
              u11 = *(const float4*)(xr1 + ip1 * 64 + 4); }        \
    if (v2) { u20 = *(const float4*)(xr2 + ip2 * 64);              \
              u21 = *(const float4*)(xr2 + ip2 * 64 + 4); }        \
  } while (0)
#define T8B_WRITE(B) do {                                          \
    bf16x8 b1 = {}, b2 = {};                                       \
    if (v1) {                                                      \
      b1[0]=(__bf16)(u10.x*g1[0]); b1[1]=(__bf16)(u10.y*g1[1]);    \
      b1[2]=(__bf16)(u10.z*g1[2]); b1[3]=(__bf16)(u10.w*g1[3]);    \
      b1[4]=(__bf16)(u11.x*g1[4]); b1[5]=(__bf16)(u11.y*g1[5]);    \
      b1[6]=(__bf16)(u11.z*g1[6]); b1[7]=(__bf16)(u11.w*g1[7]);    \
    }                                                              \
    if (v2) {                                                      \
      b2[0]=(__bf16)(u20.x*g2[0]); b2[1]=(__bf16)(u20.y*g2[1]);    \
      b2[2]=(__bf16)(u20.z*g2[2]); b2[3]=(__bf16)(u20.w*g2[3]);    \
      b2[4]=(__bf16)(u21.x*g2[4]); b2[5]=(__bf16)(u21.y*g2[5]);    \
      b2[6]=(__bf16)(u21.z*g2[6]); b2[7]=(__bf16)(u21.w*g2[7]);    \
    }                                                              \
    *(bf16x8*)&Bs[B][d1] = b1;                                     \
    *(bf16x8*)&Bs[B][d2] = b2;                                     \
  } while (0)
    T8B_LOAD(0);
    T8A(0, 0);
    T8B_WRITE(0);
    __syncthreads();
    for (int p = 0; p < P; ++p) {
      const int pb = p & 1;
      if (p + 1 < P) T8B_LOAD(p + 1);
      T8A(1, 2 * p + 1);
      COMPUTE_SWZ(0, pb, 0);
      if (p + 1 < P) T8B_WRITE(pb ^ 1);
      __syncthreads();
      if (p + 1 < P) T8A(0, 2 * p + 2);
      COMPUTE_SWZ(1, pb, 1);
      __syncthreads();
    }
#undef T8A
#undef T8B_LOAD
#undef T8B_WRITE
  }

  const int colb = n0 + wn * 32 + l16;
  __bf16* pb2 = part + ((size_t)(kc * NB + n) * CD) * K7;
#pragma unroll
  for (int fm = 0; fm < 4; ++fm)
#pragma unroll
    for (int r2 = 0; r2 < 4; ++r2) {
      const int c1 = wm * 64 + fm * 16 + lg * 4 + r2;
      __bf16* orow = pb2 + (size_t)c1 * K7 + colb;
      orow[0]  = (__bf16)acc[fm][0][r2];
      orow[16] = (__bf16)acc[fm][1][r2];
    }
}

// ---------------------------------------------------------------------------
// GEMM 2 (split-K2): M = T8 · (diag(p3)·W7). Pure-DMA, NBUF=4 counted pipeline.
// ---------------------------------------------------------------------------
__global__ __launch_bounds__(256)
void m_mfma(const __bf16* __restrict__ t8img, const __bf16* __restrict__ w7img,
            __bf16* __restrict__ part) {
  __shared__ __bf16 As[4][4096];
  __shared__ __bf16 Bs[4][2048];
  const int tile = blockIdx.x;
  const int n    = blockIdx.y;
  const int kc   = blockIdx.z;
  const int t = threadIdx.x;
  const int lane = t & 63, wid = t >> 6;
  const int wm = wid & 1, wn = wid >> 1;
  const int l16 = lane & 15, lg = lane >> 4;
  const int wb = wid * 512;

  const __bf16* aptr = t8img + ((size_t)(n * 28 + kc * 14) * 512 + t) * 8;
  const __bf16* bptr = w7img + ((size_t)(tile * 28 + kc * 14) * 256 + t) * 8;

  f32x4 acc[4][2] = {};
  const int NSTEP = 14;

#define M_STG(B, ST) do {                                          \
    gl16(aptr + (size_t)(ST) * 4096,        &As[B][wb]);           \
    gl16(aptr + (size_t)(ST) * 4096 + 2048, &As[B][wb + 2048]);    \
    gl16(bptr + (size_t)(ST) * 2048,        &Bs[B][wb]);           \
  } while (0)

  M_STG(0, 0); M_STG(1, 1); M_STG(2, 2);
  for (int st = 0; st < NSTEP - 2; ++st) {
    vw<6>();
    if (st + 3 < NSTEP) M_STG((st + 3) & 3, st + 3);
    COMPUTE_STD(st & 3, st & 3);
  }
  vw<3>(); COMPUTE_STD((NSTEP - 2) & 3, (NSTEP - 2) & 3);
  vw<0>(); COMPUTE_STD((NSTEP - 1) & 3, (NSTEP - 1) & 3);
#undef M_STG

  const int colb = tile * 64 + wn * 32 + l16;
  __bf16* pb = part + (size_t)kc * (NB * CD * K7);
#pragma unroll
  for (int fm = 0; fm < 4; ++fm)
#pragma unroll
    for (int r = 0; r < 4; ++r) {
      const int mr = n * 128 + wm * 64 + fm * 16 + lg * 4 + r;
      __bf16* orow = pb + (size_t)mr * K7 + colb;
      orow[0]  = (__bf16)acc[fm][0][r];
      orow[16] = (__bf16)acc[fm][1][r];
    }
}

// ---------------------------------------------------------------------------
// GEMM 3: out = M·Bx - t6. A=mimg DMA; B=xT pair-DMA (128B segments,
// conflict-free swizzle); 2-buf counted-vmcnt pipeline.  [proven config]
// grid flat 1024, XCD-pinned.
// ---------------------------------------------------------------------------
__global__ __launch_bounds__(256)
void out_mfma(const __bf16* __restrict__ mimg, const __bf16* __restrict__ xT,
              const __bf16* __restrict__ p4T, const float* __restrict__ w6,
              float* __restrict__ outp) {
  __shared__ __bf16 As[2][4096];
  __shared__ __bf16 Bs[2][4096];
  const int b = blockIdx.x;
  const int xcd = b & 7, slot0 = b >> 3;         // slot 0..127
  const int n = (xcd << 1) | (slot0 >> 6);
  const int i = slot0 & 63;
  const int t = threadIdx.x;
  const int lane = t & 63, wid = t >> 6;
  const int wm = wid & 1, wn = wid >> 1;
  const int l16 = lane & 15, lg = lane >> 4;
  const int wb = wid * 512;

  const __bf16* aptr = mimg + ((size_t)n * 28 * 512 + t) * 8;

  // B pair roles: 8 lanes/col, cols wid*16+(lane>>3) and +8; chunk XOR preswz
  const int colw = wid * 16 + (lane >> 3);
  const int scd8 = ((lane & 7) ^ ((lane >> 3) & 7)) * 8;
  const __bf16* bptr1 = xT + (((size_t)n * HD + i) * XROW + colw) * CD + scd8;
  const __bf16* bptr2 = bptr1 + 8 * CD;

  f32x4 acc[4][2] = {};

#define OA(B, ST) do {                                             \
    gl16(aptr + (size_t)(ST) * 4096,        &As[B][wb]);           \
    gl16(aptr + (size_t)(ST) * 4096 + 2048, &As[B][wb + 2048]);    \
  } while (0)
#define OB(B, PP) do {                                             \
    gl16(bptr1 + (PP) * 64, &Bs[B][wid * 1024]);                   \
    gl16(bptr2 + (PP) * 64, &Bs[B][wid * 1024 + 512]);             \
  } while (0)

  const int P = 14;   // pairs; 28 steps
  OA(0, 0); OB(0, 0);
  for (int p = 0; p < P - 1; ++p) {
    const int pb = p & 1;
    OA(1, 2 * p + 1);
    OB(pb ^ 1, p + 1);
    vw<4>();
    COMPUTE_SWZ(0, pb, 0);
    vw<2>();
    OA(0, 2 * p + 2);
    COMPUTE_SWZ(1, pb, 1);
    barr();
  }
  { const int pb = (P - 1) & 1;
    OA(1, 2 * P - 1);
    vw<2>();
    COMPUTE_SWZ(0, pb, 0);
    vw<0>();
    COMPUTE_SWZ(1, pb, 1);
  }
#undef OA
#undef OB

  // epilogue: subtract depthwise t6 (xT/p4T channel-contiguous reads)
  const __bf16* xTn = xT + (size_t)n * HD * XROW * CD;
#pragma unroll
  for (int fm = 0; fm < 4; ++fm) {
    const int cbase = wm * 64 + fm * 16 + lg * 4;
    const float4 wa  = *(const float4*)(w6 + cbase * 3);
    const float4 wbv = *(const float4*)(w6 + cbase * 3 + 4);
    const float4 wc  = *(const float4*)(w6 + cbase * 3 + 8);
    const float w6v[4][3] = {{wa.x, wa.y, wa.z}, {wa.w, wbv.x, wbv.y},
                             {wbv.z, wbv.w, wc.x}, {wc.y, wc.z, wc.w}};
#pragma unroll
    for (int fn = 0; fn < 2; ++fn) {
      const int jj = wn * 32 + fn * 16 + l16;
      const int jm = (jj - 1) & 63;
      const size_t ro = (size_t)(jm + 3) * CD + cbase;
      float t6v[4] = {0.f, 0.f, 0.f, 0.f};
#pragma unroll
      for (int rr = 0; rr < 3; ++rr) {
        const int ip = i + 3 * rr - 3;
        if ((unsigned)ip < (unsigned)HD) {
          const bf16x4 xv = *(const bf16x4*)(xTn + (size_t)ip * XROW * CD + ro);
          const bf16x4 pv = *(const bf16x4*)(p4T + (size_t)ip * XROW * CD + ro);
#pragma unroll
          for (int rq = 0; rq < 4; ++rq)
            t6v[rq] += w6v[rq][rr] * (float)pv[rq] * (float)xv[rq];
        }
      }
      float* obase = outp + ((size_t)(n * CD + cbase)) * SD + i * WD + jj;
#pragma unroll
      for (int rq = 0; rq < 4; ++rq)
        obase[(size_t)rq * SD] = acc[fm][fn][rq] - t6v[rq];
    }
  }
}

extern "C" void kernel_launch(void* const* d_in, const int* in_sizes, int n_in,
                              void* d_out, int out_size, void* d_ws, size_t ws_size,
                              hipStream_t stream) {
  const float* x  = (const float*)d_in[0];
  const float* p2 = (const float*)d_in[1];
  const float* p3 = (const float*)d_in[2];
  const float* p4 = (const float*)d_in[3];
  const float* w6 = (const float*)d_in[4];
  const float* w7 = (const float*)d_in[5];
  float* outp = (float*)d_out;

  const size_t e_x   = (size_t)NB * CD * SD;          // 8,388,608
  const size_t e_t8  = (size_t)NB * CD * K7;          // 1,835,008
  const size_t e_w7  = (size_t)K7 * K7;               //   802,816
  const size_t e_xp2 = (size_t)NB * CD * SD2;         // 9,961,472
  const size_t e_xT  = (size_t)NB * HD * XROW * CD;   // 9,437,184
  const size_t e_p4T = (size_t)HD * XROW * CD;        //   589,824

  const size_t base_b = (e_x + 2 * e_t8 + e_w7) * 2;              // 25,722,880
  const size_t xp2_b  = (e_xp2 + 4 * e_t8) * 2;                   // 34,603,008
  const bool   tierA  = ws_size >= base_b + xp2_b;                // 60,325,888

  __bf16* ximg  = (__bf16*)d_ws;
  __bf16* t8img = ximg + e_x;
  __bf16* mimg  = t8img + e_t8;
  __bf16* w7img = mimg + e_t8;
  __bf16* region = w7img + e_w7;
  __bf16* xp2    = tierA ? region : nullptr;
  __bf16* partT8 = tierA ? (region + e_xp2) : region;  // dead after reduce4
  __bf16* partM  = region;                             // dead after reduce2
  __bf16* xT     = region;                             // built after reduce2
  __bf16* p4T    = region + e_xT;

  dim3 blk(256);
  // main cvt (4096 blocks) + fused xp2 pad-fill tail (768 blocks)
  cvt_ximg<<<dim3(4096 + 768), blk, 0, stream>>>(x, p2, ximg, xp2);
  w7img_kernel<<<dim3(14, 14), blk, 0, stream>>>(w7, p3, w7img);

  if (tierA)
    t8_mfma<true><<<dim3(896), blk, 0, stream>>>(x, ximg, xp2, p2, partT8);
  else
    t8_mfma<false><<<dim3(896), blk, 0, stream>>>(x, ximg, nullptr, p2, partT8);
  reduce_img<4><<<dim3(896), blk, 0, stream>>>(partT8, t8img, 1.f / 64.f);

  m_mfma<<<dim3(14, 16, 2), blk, 0, stream>>>(t8img, w7img, partM);
  reduce_img<2><<<dim3(896), blk, 0, stream>>>(partM, mimg, 0.033407655f);

  // fused: xT (y<NB) + p4T (y==NB)
  xt_kernel<<<dim3(HD, NB + 1), blk, 0, stream>>>(x, p4, xT, p4T);
  out_mfma<<<dim3(1024), blk, 0, stream>>>(mimg, xT, p4T, w6, outp);
}